// Round 1
// baseline (725.067 us; speedup 1.0000x reference)
//
#include <hip/hip_runtime.h>
#include <hip/hip_bf16.h>
#include <math.h>

#define M_BATCH   4096
#define K_IN      4096
#define N_OUT     4096
#define NELEM     16777216   // 4096*4096

typedef __bf16 bf16;
typedef bf16  bf16x8 __attribute__((ext_vector_type(8)));
typedef float f32x4  __attribute__((ext_vector_type(4)));

__device__ __forceinline__ float softplusf(float x) {
    return (x > 20.0f) ? x : log1pf(expf(x));
}

__device__ __forceinline__ unsigned short f2bf_bits(float x) {
    bf16 b = (bf16)x;
    return __builtin_bit_cast(unsigned short, b);
}

// async global->LDS, 16B per lane. LDS dst must be wave-uniform base + lane*16.
__device__ __forceinline__ void gload_lds16(const void* g, void* l) {
    __builtin_amdgcn_global_load_lds(
        (__attribute__((address_space(1))) void*)g,
        (__attribute__((address_space(3))) void*)l,
        16, 0, 0);
}

// ---------------------------------------------------------------------------
// prep_a: mu_in (fp32) -> A (bf16), A2 = (mu_in^2) (bf16). 4 elems/thread.
// ---------------------------------------------------------------------------
__global__ __launch_bounds__(256) void prep_a(const float4* __restrict__ mu,
                                              ushort4* __restrict__ A,
                                              ushort4* __restrict__ A2) {
    const int i = blockIdx.x * 256 + threadIdx.x;   // grid covers NELEM/4 exactly
    const float4 v = mu[i];
    ushort4 a, a2;
    a.x  = f2bf_bits(v.x);       a.y  = f2bf_bits(v.y);
    a.z  = f2bf_bits(v.z);       a.w  = f2bf_bits(v.w);
    a2.x = f2bf_bits(v.x * v.x); a2.y = f2bf_bits(v.y * v.y);
    a2.z = f2bf_bits(v.z * v.z); a2.w = f2bf_bits(v.w * v.w);
    A[i]  = a;
    A2[i] = a2;
}

// ---------------------------------------------------------------------------
// prep_w: transpose-convert w_mu -> Wmu_t (N x K bf16), softplus(w_sigma) ->
// Wsg_t (N x K bf16); fused KL partial sums per block.
// grid (64,64), block 256. 64x64 tiles via LDS.
// ---------------------------------------------------------------------------
__global__ __launch_bounds__(256) void prep_w(const float* __restrict__ wmu,
                                              const float* __restrict__ wsg,
                                              bf16* __restrict__ Wmu_t,
                                              bf16* __restrict__ Wsg_t,
                                              float* __restrict__ partials) {
    __shared__ bf16 tmu[64][65];
    __shared__ bf16 tsg[64][65];
    __shared__ float red[256];

    const int t  = threadIdx.x;
    const int ti = blockIdx.y;          // i (K) tile
    const int tj = blockIdx.x;          // o (N) tile
    const int r  = t >> 4;              // 0..15
    const int c4 = (t & 15) << 2;       // 0,4,..,60

    float s_abs = 0.f, s_sp = 0.f, s_log = 0.f;

    for (int rr = 0; rr < 64; rr += 16) {
        const int row = rr + r;
        const size_t goff = (size_t)(ti * 64 + row) * N_OUT + tj * 64 + c4;
        const float4 vm = *(const float4*)(wmu + goff);
        const float4 vs = *(const float4*)(wsg + goff);
        const float sp0 = softplusf(vs.x), sp1 = softplusf(vs.y);
        const float sp2 = softplusf(vs.z), sp3 = softplusf(vs.w);
        s_abs += fabsf(vm.x) + fabsf(vm.y) + fabsf(vm.z) + fabsf(vm.w);
        s_sp  += sp0 + sp1 + sp2 + sp3;
        s_log += logf(sp0) + logf(sp1) + logf(sp2) + logf(sp3);
        tmu[row][c4 + 0] = (bf16)vm.x; tmu[row][c4 + 1] = (bf16)vm.y;
        tmu[row][c4 + 2] = (bf16)vm.z; tmu[row][c4 + 3] = (bf16)vm.w;
        tsg[row][c4 + 0] = (bf16)sp0;  tsg[row][c4 + 1] = (bf16)sp1;
        tsg[row][c4 + 2] = (bf16)sp2;  tsg[row][c4 + 3] = (bf16)sp3;
    }
    __syncthreads();

    // transposed write: Wt[o][i] = tile[i][o]
    for (int cc = 0; cc < 64; cc += 16) {
        const int j  = cc + r;      // original col (o) within tile
        const int i0 = c4;          // original row (i) within tile
        ushort4 om, os;
        om.x = __builtin_bit_cast(unsigned short, tmu[i0 + 0][j]);
        om.y = __builtin_bit_cast(unsigned short, tmu[i0 + 1][j]);
        om.z = __builtin_bit_cast(unsigned short, tmu[i0 + 2][j]);
        om.w = __builtin_bit_cast(unsigned short, tmu[i0 + 3][j]);
        os.x = __builtin_bit_cast(unsigned short, tsg[i0 + 0][j]);
        os.y = __builtin_bit_cast(unsigned short, tsg[i0 + 1][j]);
        os.z = __builtin_bit_cast(unsigned short, tsg[i0 + 2][j]);
        os.w = __builtin_bit_cast(unsigned short, tsg[i0 + 3][j]);
        const size_t o = (size_t)(tj * 64 + j) * K_IN + ti * 64 + i0;
        *(ushort4*)(Wmu_t + o) = om;
        *(ushort4*)(Wsg_t + o) = os;
    }

    // KL partial reduction (3 values per block)
    const int bid = blockIdx.y * 64 + blockIdx.x;   // 0..4095
    float vals[3] = { s_log, s_sp, s_abs };
    for (int v = 0; v < 3; v++) {
        __syncthreads();
        red[t] = vals[v];
        __syncthreads();
        for (int s = 128; s > 0; s >>= 1) {
            if (t < s) red[t] += red[t + s];
            __syncthreads();
        }
        if (t == 0) partials[v * 4096 + bid] = red[0];
    }
}

// ---------------------------------------------------------------------------
// gemm_bf16: C[M,N] = A[M,K](bf16) * Bt[N,K]^T(bf16) + bias  (fp32 out)
// m97 structure: 128x128 tile, BK=32, global_load_lds x16, 16x16x32 MFMA.
// block 256 (4 waves, 2x2), each wave 64x64 via 4x4 MFMA frags.
// ---------------------------------------------------------------------------
__global__ __launch_bounds__(256) void gemm_bf16(const bf16* __restrict__ A,
                                                 const bf16* __restrict__ Bt,
                                                 const float* __restrict__ bias,
                                                 float* __restrict__ C,
                                                 const int spBias) {
    __shared__ bf16 As[128 * 32];   // row-major, row stride 32 bf16 (64B)
    __shared__ bf16 Bs[128 * 32];

    const int t = threadIdx.x;
    const int bx = blockIdx.x;      // N tile
    const int by = blockIdx.y;      // M tile
    const int rowBase = by * 128;
    const int colBase = bx * 128;

    // staging: thread t -> row t/4 (and +64), byte (t%4)*16 within 64B row.
    // wave-local LDS addr = waveBase + lane*16  (global_load_lds requirement)
    const int srow  = t >> 2;
    const int sbyte = (t & 3) << 4;
    const char* agp = (const char*)(A  + (size_t)(rowBase + srow) * K_IN) + sbyte;
    const char* bgp = (const char*)(Bt + (size_t)(colBase + srow) * K_IN) + sbyte;
    char* alp = (char*)As + srow * 64 + sbyte;
    char* blp = (char*)Bs + srow * 64 + sbyte;
    const size_t rowskip = (size_t)64 * K_IN * 2;   // 64 rows down, bytes

    const int lane = t & 63;
    const int wave = t >> 6;
    const int wm = (wave >> 1) << 6;     // wave row offset in tile
    const int wn = (wave & 1) << 6;      // wave col offset in tile
    const int frow = lane & 15;
    const int fko  = (lane >> 4) << 3;   // k element offset (quad*8)

    f32x4 zero = { 0.f, 0.f, 0.f, 0.f };
    f32x4 acc[4][4];
#pragma unroll
    for (int i = 0; i < 4; i++)
#pragma unroll
        for (int j = 0; j < 4; j++) acc[i][j] = zero;

    for (int k0 = 0; k0 < K_IN; k0 += 32) {
        const int kb = k0 * 2;  // byte advance along K
        gload_lds16(agp + kb,            alp);
        gload_lds16(agp + kb + rowskip,  alp + 64 * 64);
        gload_lds16(bgp + kb,            blp);
        gload_lds16(bgp + kb + rowskip,  blp + 64 * 64);
        __syncthreads();

        bf16x8 af[4], bfr[4];
#pragma unroll
        for (int i = 0; i < 4; i++)
            af[i] = *(const bf16x8*)(As + (wm + i * 16 + frow) * 32 + fko);
#pragma unroll
        for (int j = 0; j < 4; j++)
            bfr[j] = *(const bf16x8*)(Bs + (wn + j * 16 + frow) * 32 + fko);
#pragma unroll
        for (int i = 0; i < 4; i++)
#pragma unroll
            for (int j = 0; j < 4; j++)
                acc[i][j] = __builtin_amdgcn_mfma_f32_16x16x32_bf16(
                    af[i], bfr[j], acc[i][j], 0, 0, 0);
        __syncthreads();
    }

    // epilogue: C/D layout col=lane&15, row=(lane>>4)*4+reg (m89-verified)
    const int r0 = (lane >> 4) << 2;
#pragma unroll
    for (int j = 0; j < 4; j++) {
        const int c = colBase + wn + j * 16 + (lane & 15);
        float b = bias[c];
        if (spBias) b = softplusf(b);
#pragma unroll
        for (int i = 0; i < 4; i++) {
            const int rbase = rowBase + wm + i * 16 + r0;
#pragma unroll
            for (int reg = 0; reg < 4; reg++)
                C[(size_t)(rbase + reg) * N_OUT + c] = acc[i][j][reg] + b;
        }
    }
}

// ---------------------------------------------------------------------------
// kl_finish: reduce partials (3 x n) in double, write scalar kl.
// ---------------------------------------------------------------------------
__global__ __launch_bounds__(256) void kl_finish(const float* __restrict__ partials,
                                                 const int n,
                                                 float* __restrict__ out) {
    __shared__ double red[256];
    const int t = threadIdx.x;
    double sums[3];
    for (int v = 0; v < 3; v++) {
        double a = 0.0;
        for (int i = t; i < n; i += 256) a += (double)partials[v * n + i];
        red[t] = a;
        __syncthreads();
        for (int s = 128; s > 0; s >>= 1) {
            if (t < s) red[t] += red[t + s];
            __syncthreads();
        }
        sums[v] = red[0];
        __syncthreads();
    }
    if (t == 0) {
        const double mean_log = sums[0] / 16777216.0;
        const double mean_sp  = sums[1] / 16777216.0;
        const double kl = -0.5 * (4096.0 * mean_log - sums[2] - 4096.0 * mean_sp);
        out[0] = (float)kl;
    }
}

// ---------------------------------------------------------------------------
// Fallback (only if ws too small): naive fp32 dual GEMM + partials.
// ---------------------------------------------------------------------------
__global__ void fb_partials(const float* __restrict__ wmu,
                            const float* __restrict__ wsg,
                            float* __restrict__ partials) {
    __shared__ float red[256];
    const int t = threadIdx.x;
    float s_abs = 0.f, s_sp = 0.f, s_log = 0.f;
    for (int i = blockIdx.x * 256 + t; i < NELEM; i += 1024 * 256) {
        s_abs += fabsf(wmu[i]);
        const float sp = softplusf(wsg[i]);
        s_sp += sp;
        s_log += logf(sp);
    }
    float vals[3] = { s_log, s_sp, s_abs };
    for (int v = 0; v < 3; v++) {
        __syncthreads();
        red[t] = vals[v];
        __syncthreads();
        for (int s = 128; s > 0; s >>= 1) {
            if (t < s) red[t] += red[t + s];
            __syncthreads();
        }
        if (t == 0) partials[v * 1024 + blockIdx.x] = red[0];
    }
}

__global__ void fb_gemm(const float* __restrict__ A,
                        const float* __restrict__ Wm,
                        const float* __restrict__ Ws,
                        const float* __restrict__ bmu,
                        const float* __restrict__ bsg,
                        float* __restrict__ Cmu,
                        float* __restrict__ Csg) {
    __shared__ float As_[16][17], Bm[16][17], Bs_[16][17];
    const int tx = threadIdx.x, ty = threadIdx.y;
    const int row = blockIdx.y * 16 + ty;
    const int col = blockIdx.x * 16 + tx;
    float am = 0.f, as = 0.f;
    for (int k0 = 0; k0 < K_IN; k0 += 16) {
        As_[ty][tx] = A[(size_t)row * K_IN + k0 + tx];
        Bm[ty][tx]  = Wm[(size_t)(k0 + ty) * N_OUT + col];
        Bs_[ty][tx] = softplusf(Ws[(size_t)(k0 + ty) * N_OUT + col]);
        __syncthreads();
#pragma unroll
        for (int kk = 0; kk < 16; kk++) {
            const float av = As_[ty][kk];
            am += av * Bm[kk][tx];
            as += av * av * Bs_[kk][tx];
        }
        __syncthreads();
    }
    Cmu[(size_t)row * N_OUT + col] = am + bmu[col];
    Csg[(size_t)row * N_OUT + col] = as + softplusf(bsg[col]);
}

// ---------------------------------------------------------------------------
extern "C" void kernel_launch(void* const* d_in, const int* in_sizes, int n_in,
                              void* d_out, int out_size, void* d_ws, size_t ws_size,
                              hipStream_t stream) {
    const float* mu_in   = (const float*)d_in[0];
    // d_in[1] (sigma_in) unused by the reference
    const float* w_mu    = (const float*)d_in[2];
    const float* w_sigma = (const float*)d_in[3];
    const float* b_mu    = (const float*)d_in[4];
    const float* b_sigma = (const float*)d_in[5];

    float* out_mu  = (float*)d_out;
    float* out_sig = out_mu + (size_t)NELEM;
    float* out_kl  = out_mu + 2 * (size_t)NELEM;

    const size_t mat  = (size_t)NELEM;
    const size_t need = mat * 2 * 4 /* 4 bf16 matrices */ + 3 * 4096 * sizeof(float);

    if (ws_size >= need) {
        bf16* A      = (bf16*)d_ws;
        bf16* A2     = A + mat;
        bf16* Wmu_t  = A2 + mat;
        bf16* Wsg_t  = Wmu_t + mat;
        float* parts = (float*)(Wsg_t + mat);

        prep_a<<<NELEM / 4 / 256, 256, 0, stream>>>(
            (const float4*)mu_in, (ushort4*)A, (ushort4*)A2);
        prep_w<<<dim3(64, 64), 256, 0, stream>>>(
            w_mu, w_sigma, Wmu_t, Wsg_t, parts);
        gemm_bf16<<<dim3(32, 32), 256, 0, stream>>>(A,  Wmu_t, b_mu,    out_mu,  0);
        gemm_bf16<<<dim3(32, 32), 256, 0, stream>>>(A2, Wsg_t, b_sigma, out_sig, 1);
        kl_finish<<<1, 256, 0, stream>>>(parts, 4096, out_kl);
    } else {
        // emergency fallback: slow but correct fp32 path (needs 12KB ws)
        float* parts = (float*)d_ws;
        fb_partials<<<1024, 256, 0, stream>>>(w_mu, w_sigma, parts);
        fb_gemm<<<dim3(256, 256), dim3(16, 16), 0, stream>>>(
            mu_in, w_mu, w_sigma, b_mu, b_sigma, out_mu, out_sig);
        kl_finish<<<1, 256, 0, stream>>>(parts, 1024, out_kl);
    }
}

// Round 2
// 638.100 us; speedup vs baseline: 1.1363x; 1.1363x over previous
//
#include <hip/hip_runtime.h>
#include <hip/hip_bf16.h>
#include <math.h>

#define M_BATCH   4096
#define K_IN      4096
#define N_OUT     4096
#define NELEM     16777216   // 4096*4096

typedef __bf16 bf16;
typedef bf16  bf16x8 __attribute__((ext_vector_type(8)));
typedef float f32x4  __attribute__((ext_vector_type(4)));

// fast softplus: hardware v_exp/v_log, poly for small e (w_sigma in [-12,-2.2])
__device__ __forceinline__ float softplus_fast(float x) {
    if (x > 15.f) return x;
    const float e = __expf(x);
    if (e < 0.0883f)  // log1p(e) = e - e^2/2 + e^3/3, trunc err < 2e-6 rel
        return e * (1.f + e * (-0.5f + e * 0.3333333f));
    return __logf(1.f + e);
}

__device__ __forceinline__ unsigned short f2bf_bits(float x) {
    bf16 b = (bf16)x;
    return __builtin_bit_cast(unsigned short, b);
}

// async global->LDS, 16B per lane. LDS dst must be wave-uniform base + lane*16.
__device__ __forceinline__ void gload_lds16(const void* g, void* l) {
    __builtin_amdgcn_global_load_lds(
        (__attribute__((address_space(1))) void*)g,
        (__attribute__((address_space(3))) void*)l,
        16, 0, 0);
}

// ---------------------------------------------------------------------------
// prep_a: mu_in (fp32) -> A (bf16), A2 = (mu_in^2) (bf16). 4 elems/thread.
// ---------------------------------------------------------------------------
__global__ __launch_bounds__(256) void prep_a(const float4* __restrict__ mu,
                                              ushort4* __restrict__ A,
                                              ushort4* __restrict__ A2) {
    const int i = blockIdx.x * 256 + threadIdx.x;   // grid covers NELEM/4 exactly
    const float4 v = mu[i];
    ushort4 a, a2;
    a.x  = f2bf_bits(v.x);       a.y  = f2bf_bits(v.y);
    a.z  = f2bf_bits(v.z);       a.w  = f2bf_bits(v.w);
    a2.x = f2bf_bits(v.x * v.x); a2.y = f2bf_bits(v.y * v.y);
    a2.z = f2bf_bits(v.z * v.z); a2.w = f2bf_bits(v.w * v.w);
    A[i]  = a;
    A2[i] = a2;
}

// ---------------------------------------------------------------------------
// prep_w: transpose-convert w_mu -> Wmu_t (N x K bf16), softplus(w_sigma) ->
// Wsg_t (N x K bf16); fused KL partial sums per block. Fast transcendentals.
// grid (64,64), block 256. 64x64 tiles via LDS.
// ---------------------------------------------------------------------------
__global__ __launch_bounds__(256) void prep_w(const float* __restrict__ wmu,
                                              const float* __restrict__ wsg,
                                              bf16* __restrict__ Wmu_t,
                                              bf16* __restrict__ Wsg_t,
                                              float* __restrict__ partials) {
    __shared__ bf16 tmu[64][65];
    __shared__ bf16 tsg[64][65];
    __shared__ float red[256];

    const int t  = threadIdx.x;
    const int ti = blockIdx.y;          // i (K) tile
    const int tj = blockIdx.x;          // o (N) tile
    const int r  = t >> 4;              // 0..15
    const int c4 = (t & 15) << 2;       // 0,4,..,60

    float s_abs = 0.f, s_sp = 0.f, s_log = 0.f;

    for (int rr = 0; rr < 64; rr += 16) {
        const int row = rr + r;
        const size_t goff = (size_t)(ti * 64 + row) * N_OUT + tj * 64 + c4;
        const float4 vm = *(const float4*)(wmu + goff);
        const float4 vs = *(const float4*)(wsg + goff);
        const float sp0 = softplus_fast(vs.x), sp1 = softplus_fast(vs.y);
        const float sp2 = softplus_fast(vs.z), sp3 = softplus_fast(vs.w);
        s_abs += fabsf(vm.x) + fabsf(vm.y) + fabsf(vm.z) + fabsf(vm.w);
        s_sp  += sp0 + sp1 + sp2 + sp3;
        s_log += __logf(sp0) + __logf(sp1) + __logf(sp2) + __logf(sp3);
        tmu[row][c4 + 0] = (bf16)vm.x; tmu[row][c4 + 1] = (bf16)vm.y;
        tmu[row][c4 + 2] = (bf16)vm.z; tmu[row][c4 + 3] = (bf16)vm.w;
        tsg[row][c4 + 0] = (bf16)sp0;  tsg[row][c4 + 1] = (bf16)sp1;
        tsg[row][c4 + 2] = (bf16)sp2;  tsg[row][c4 + 3] = (bf16)sp3;
    }
    __syncthreads();

    // transposed write: Wt[o][i] = tile[i][o]
    for (int cc = 0; cc < 64; cc += 16) {
        const int j  = cc + r;      // original col (o) within tile
        const int i0 = c4;          // original row (i) within tile
        ushort4 om, os;
        om.x = __builtin_bit_cast(unsigned short, tmu[i0 + 0][j]);
        om.y = __builtin_bit_cast(unsigned short, tmu[i0 + 1][j]);
        om.z = __builtin_bit_cast(unsigned short, tmu[i0 + 2][j]);
        om.w = __builtin_bit_cast(unsigned short, tmu[i0 + 3][j]);
        os.x = __builtin_bit_cast(unsigned short, tsg[i0 + 0][j]);
        os.y = __builtin_bit_cast(unsigned short, tsg[i0 + 1][j]);
        os.z = __builtin_bit_cast(unsigned short, tsg[i0 + 2][j]);
        os.w = __builtin_bit_cast(unsigned short, tsg[i0 + 3][j]);
        const size_t o = (size_t)(tj * 64 + j) * K_IN + ti * 64 + i0;
        *(ushort4*)(Wmu_t + o) = om;
        *(ushort4*)(Wsg_t + o) = os;
    }

    // KL partial reduction (3 values per block)
    const int bid = blockIdx.y * 64 + blockIdx.x;   // 0..4095
    float vals[3] = { s_log, s_sp, s_abs };
    for (int v = 0; v < 3; v++) {
        __syncthreads();
        red[t] = vals[v];
        __syncthreads();
        for (int s = 128; s > 0; s >>= 1) {
            if (t < s) red[t] += red[t + s];
            __syncthreads();
        }
        if (t == 0) partials[v * 4096 + bid] = red[0];
    }
}

// ---------------------------------------------------------------------------
// gemm_bf16: C[M,N] = A[M,K](bf16) * Bt[N,K]^T(bf16) + bias  (fp32 out)
// m97 structure: 128x128 tile, BK=32, global_load_lds x16, 16x16x32 MFMA.
// blockIdx.z selects {mu, sigma} problem. LDS chunk-swizzle kills the 8-way
// ds_read bank conflicts: row r's k-chunk c lives at position (c+(r>>1))&3.
// ---------------------------------------------------------------------------
__global__ __launch_bounds__(256) void gemm_bf16(const bf16* __restrict__ A1,
                                                 const bf16* __restrict__ Bt1,
                                                 const float* __restrict__ bias1,
                                                 float* __restrict__ C1,
                                                 const bf16* __restrict__ A2_,
                                                 const bf16* __restrict__ Bt2,
                                                 const float* __restrict__ bias2,
                                                 float* __restrict__ C2) {
    __shared__ bf16 As[128 * 32];   // row-major, row stride 32 bf16 (64B), swizzled
    __shared__ bf16 Bs[128 * 32];

    const int z = blockIdx.z;
    const bf16*  A    = z ? A2_   : A1;
    const bf16*  Bt   = z ? Bt2   : Bt1;
    const float* bias = z ? bias2 : bias1;
    float*       C    = z ? C2    : C1;

    const int t = threadIdx.x;
    const int rowBase = blockIdx.y * 128;
    const int colBase = blockIdx.x * 128;

    // staging: thread t -> row t/4 (and +64), LDS position slot (t&3).
    // global chunk fetched = (pos - (row>>1)) & 3  (swizzle inverse; same for
    // row and row+64 since 64>>1 = 32 ≡ 0 mod 4). Same 64B segment -> coalesced.
    const int srow  = t >> 2;
    const int cg    = ((t & 3) - ((t >> 3) & 3)) & 3;   // global chunk index
    const char* agp = (const char*)(A  + (size_t)(rowBase + srow) * K_IN) + (cg << 4);
    const char* bgp = (const char*)(Bt + (size_t)(colBase + srow) * K_IN) + (cg << 4);
    char* alp = (char*)As + t * 16;            // wave-uniform base + lane*16
    char* blp = (char*)Bs + t * 16;
    const size_t rowskip = (size_t)64 * K_IN * 2;   // 64 rows down, bytes

    const int lane = t & 63;
    const int wave = t >> 6;
    const int wm = (wave >> 1) << 6;     // wave row offset in tile
    const int wn = (wave & 1) << 6;      // wave col offset in tile
    const int frow = lane & 15;
    // swizzled chunk element offset; (wm|wn)/2 and 8i are ≡0 mod 4 -> lane-const
    const int ko2 = ((((lane >> 4) + (frow >> 1)) & 3) << 3);

    f32x4 zero = { 0.f, 0.f, 0.f, 0.f };
    f32x4 acc[4][4];
#pragma unroll
    for (int i = 0; i < 4; i++)
#pragma unroll
        for (int j = 0; j < 4; j++) acc[i][j] = zero;

    for (int k0 = 0; k0 < K_IN; k0 += 32) {
        const int kb = k0 * 2;  // byte advance along K
        gload_lds16(agp + kb,            alp);
        gload_lds16(agp + kb + rowskip,  alp + 64 * 64);
        gload_lds16(bgp + kb,            blp);
        gload_lds16(bgp + kb + rowskip,  blp + 64 * 64);
        __syncthreads();

        bf16x8 af[4], bfr[4];
#pragma unroll
        for (int i = 0; i < 4; i++)
            af[i] = *(const bf16x8*)(As + (wm + i * 16 + frow) * 32 + ko2);
#pragma unroll
        for (int j = 0; j < 4; j++)
            bfr[j] = *(const bf16x8*)(Bs + (wn + j * 16 + frow) * 32 + ko2);
#pragma unroll
        for (int i = 0; i < 4; i++)
#pragma unroll
            for (int j = 0; j < 4; j++)
                acc[i][j] = __builtin_amdgcn_mfma_f32_16x16x32_bf16(
                    af[i], bfr[j], acc[i][j], 0, 0, 0);
        __syncthreads();
    }

    // epilogue: C/D layout col=lane&15, row=(lane>>4)*4+reg (m89-verified)
    const int r0 = (lane >> 4) << 2;
#pragma unroll
    for (int j = 0; j < 4; j++) {
        const int c = colBase + wn + j * 16 + (lane & 15);
        float b = bias[c];
        if (z) b = softplus_fast(b);
#pragma unroll
        for (int i = 0; i < 4; i++) {
            const int rbase = rowBase + wm + i * 16 + r0;
#pragma unroll
            for (int reg = 0; reg < 4; reg++)
                C[(size_t)(rbase + reg) * N_OUT + c] = acc[i][j][reg] + b;
        }
    }
}

// ---------------------------------------------------------------------------
// kl_finish: reduce partials (3 x n) in double, write scalar kl.
// ---------------------------------------------------------------------------
__global__ __launch_bounds__(256) void kl_finish(const float* __restrict__ partials,
                                                 const int n,
                                                 float* __restrict__ out) {
    __shared__ double red[256];
    const int t = threadIdx.x;
    double sums[3];
    for (int v = 0; v < 3; v++) {
        double a = 0.0;
        for (int i = t; i < n; i += 256) a += (double)partials[v * n + i];
        red[t] = a;
        __syncthreads();
        for (int s = 128; s > 0; s >>= 1) {
            if (t < s) red[t] += red[t + s];
            __syncthreads();
        }
        sums[v] = red[0];
        __syncthreads();
    }
    if (t == 0) {
        const double mean_log = sums[0] / 16777216.0;
        const double mean_sp  = sums[1] / 16777216.0;
        const double kl = -0.5 * (4096.0 * mean_log - sums[2] - 4096.0 * mean_sp);
        out[0] = (float)kl;
    }
}

// ---------------------------------------------------------------------------
// Fallback (only if ws too small): naive fp32 dual GEMM + partials.
// ---------------------------------------------------------------------------
__global__ void fb_partials(const float* __restrict__ wmu,
                            const float* __restrict__ wsg,
                            float* __restrict__ partials) {
    __shared__ float red[256];
    const int t = threadIdx.x;
    float s_abs = 0.f, s_sp = 0.f, s_log = 0.f;
    for (int i = blockIdx.x * 256 + t; i < NELEM; i += 1024 * 256) {
        s_abs += fabsf(wmu[i]);
        const float sp = softplus_fast(wsg[i]);
        s_sp += sp;
        s_log += __logf(sp);
    }
    float vals[3] = { s_log, s_sp, s_abs };
    for (int v = 0; v < 3; v++) {
        __syncthreads();
        red[t] = vals[v];
        __syncthreads();
        for (int s = 128; s > 0; s >>= 1) {
            if (t < s) red[t] += red[t + s];
            __syncthreads();
        }
        if (t == 0) partials[v * 1024 + blockIdx.x] = red[0];
    }
}

__global__ void fb_gemm(const float* __restrict__ A,
                        const float* __restrict__ Wm,
                        const float* __restrict__ Ws,
                        const float* __restrict__ bmu,
                        const float* __restrict__ bsg,
                        float* __restrict__ Cmu,
                        float* __restrict__ Csg) {
    __shared__ float As_[16][17], Bm[16][17], Bs_[16][17];
    const int tx = threadIdx.x, ty = threadIdx.y;
    const int row = blockIdx.y * 16 + ty;
    const int col = blockIdx.x * 16 + tx;
    float am = 0.f, as = 0.f;
    for (int k0 = 0; k0 < K_IN; k0 += 16) {
        As_[ty][tx] = A[(size_t)row * K_IN + k0 + tx];
        Bm[ty][tx]  = Wm[(size_t)(k0 + ty) * N_OUT + col];
        Bs_[ty][tx] = softplus_fast(Ws[(size_t)(k0 + ty) * N_OUT + col]);
        __syncthreads();
#pragma unroll
        for (int kk = 0; kk < 16; kk++) {
            const float av = As_[ty][kk];
            am += av * Bm[kk][tx];
            as += av * av * Bs_[kk][tx];
        }
        __syncthreads();
    }
    Cmu[(size_t)row * N_OUT + col] = am + bmu[col];
    Csg[(size_t)row * N_OUT + col] = as + softplus_fast(bsg[col]);
}

// ---------------------------------------------------------------------------
extern "C" void kernel_launch(void* const* d_in, const int* in_sizes, int n_in,
                              void* d_out, int out_size, void* d_ws, size_t ws_size,
                              hipStream_t stream) {
    const float* mu_in   = (const float*)d_in[0];
    // d_in[1] (sigma_in) unused by the reference
    const float* w_mu    = (const float*)d_in[2];
    const float* w_sigma = (const float*)d_in[3];
    const float* b_mu    = (const float*)d_in[4];
    const float* b_sigma = (const float*)d_in[5];

    float* out_mu  = (float*)d_out;
    float* out_sig = out_mu + (size_t)NELEM;
    float* out_kl  = out_mu + 2 * (size_t)NELEM;

    const size_t mat  = (size_t)NELEM;
    const size_t need = mat * 2 * 4 /* 4 bf16 matrices */ + 3 * 4096 * sizeof(float);

    if (ws_size >= need) {
        bf16* A      = (bf16*)d_ws;
        bf16* A2     = A + mat;
        bf16* Wmu_t  = A2 + mat;
        bf16* Wsg_t  = Wmu_t + mat;
        float* parts = (float*)(Wsg_t + mat);

        prep_a<<<NELEM / 4 / 256, 256, 0, stream>>>(
            (const float4*)mu_in, (ushort4*)A, (ushort4*)A2);
        prep_w<<<dim3(64, 64), 256, 0, stream>>>(
            w_mu, w_sigma, Wmu_t, Wsg_t, parts);
        gemm_bf16<<<dim3(32, 32, 2), 256, 0, stream>>>(
            A, Wmu_t, b_mu, out_mu, A2, Wsg_t, b_sigma, out_sig);
        kl_finish<<<1, 256, 0, stream>>>(parts, 4096, out_kl);
    } else {
        // emergency fallback: slow but correct fp32 path (needs 12KB ws)
        float* parts = (float*)d_ws;
        fb_partials<<<1024, 256, 0, stream>>>(w_mu, w_sigma, parts);
        fb_gemm<<<dim3(256, 256), dim3(16, 16), 0, stream>>>(
            mu_in, w_mu, w_sigma, b_mu, b_sigma, out_mu, out_sig);
        kl_finish<<<1, 256, 0, stream>>>(parts, 1024, out_kl);
    }
}